// Round 2
// baseline (394.851 us; speedup 1.0000x reference)
//
#include <hip/hip_runtime.h>

typedef unsigned short u16;
typedef __attribute__((ext_vector_type(4))) float f32x4;
typedef __attribute__((ext_vector_type(8))) short s16x8;
typedef __attribute__((ext_vector_type(4))) unsigned short u16x4;

static __device__ __forceinline__ u16 f2bf(float f) {
    unsigned int x = __float_as_uint(f);
    x += 0x7fffu + ((x >> 16) & 1u);           // round-to-nearest-even
    return (u16)(x >> 16);
}

// ---------------- Stage 1: pooled[b][c] = mean_{h,w} x[b,c,h,w] -------------
// grid 8192 (= B*C), block 256
__global__ __launch_bounds__(256) void pool_kernel(const float* __restrict__ x,
                                                   float* __restrict__ pooled) {
    int bc = blockIdx.x;
    const float* p = x + (size_t)bc * 3136;
    float s = 0.f;
    for (int i = threadIdx.x; i < 784; i += 256) {       // 784*4 = 3136
        f32x4 v = *(const f32x4*)(p + i * 4);
        s += v.x + v.y + v.z + v.w;
    }
#pragma unroll
    for (int off = 32; off; off >>= 1) s += __shfl_xor(s, off);
    __shared__ float red[4];
    int lane = threadIdx.x & 63, wave = threadIdx.x >> 6;
    if (lane == 0) red[wave] = s;
    __syncthreads();
    if (threadIdx.x == 0)
        pooled[bc] = (red[0] + red[1] + red[2] + red[3]) * (1.0f / 3136.0f);
}

// ---------------- Stage 2: h[b][i] = relu(sum_j pooled[b][j]*fc1_w[i][j]) ---
// grid 2048 (= 32 b * 64), block 256 (4 waves -> 4 outputs i)
__global__ __launch_bounds__(256) void fc1_kernel(const float* __restrict__ pooled,
                                                  const float* __restrict__ w,
                                                  float* __restrict__ h) {
    __shared__ float pv[256];
    int b = blockIdx.x >> 6;
    pv[threadIdx.x] = pooled[b * 256 + threadIdx.x];
    __syncthreads();
    int lane = threadIdx.x & 63, wave = threadIdx.x >> 6;
    int i = ((blockIdx.x & 63) << 2) + wave;
    f32x4 v = *(const f32x4*)(w + i * 256 + lane * 4);
    float s = v.x * pv[lane * 4 + 0] + v.y * pv[lane * 4 + 1] +
              v.z * pv[lane * 4 + 2] + v.w * pv[lane * 4 + 3];
#pragma unroll
    for (int off = 32; off; off >>= 1) s += __shfl_xor(s, off);
    if (lane == 0) h[b * 256 + i] = fmaxf(s, 0.f);
}

// ---------------- Stage 3: kern[b][oc] = sum_j h[b][j]*fc2_w[oc][j] + b -----
// grid 8192 (= 32 b * 256), block 256 (4 waves -> 4 outputs oc)
__global__ __launch_bounds__(256) void fc2_kernel(const float* __restrict__ h,
                                                  const float* __restrict__ w,
                                                  const float* __restrict__ bias,
                                                  float* __restrict__ kern) {
    __shared__ float hv[256];
    int b = blockIdx.x >> 8;
    hv[threadIdx.x] = h[b * 256 + threadIdx.x];
    __syncthreads();
    int lane = threadIdx.x & 63, wave = threadIdx.x >> 6;
    int i = ((blockIdx.x & 255) << 2) + wave;
    f32x4 v = *(const f32x4*)(w + i * 256 + lane * 4);
    float s = v.x * hv[lane * 4 + 0] + v.y * hv[lane * 4 + 1] +
              v.z * hv[lane * 4 + 2] + v.w * hv[lane * 4 + 3];
#pragma unroll
    for (int off = 32; off; off >>= 1) s += __shfl_xor(s, off);
    if (lane == 0) kern[b * 1024 + i] = s + bias[i];
}

// ---------------- Stage 4: dynw[b][o][p][c] = bf16(sigmoid(cw)*weight) -----
// cw[b,o,c,p] = sum_t kern[b, c*4+t] * cog[o, t, p]
// layout [b][o][p][c] so conv A-fragments (8 consecutive c) are contiguous.
// grid 18432, block 256; each thread does 4 consecutive c for one (b,o,p).
__global__ __launch_bounds__(256) void dynw_kernel(const float* __restrict__ kern,
                                                   const float* __restrict__ cogw,
                                                   const float* __restrict__ wgt,
                                                   u16* __restrict__ dynw) {
    int idx = blockIdx.x * 256 + threadIdx.x;   // ((b*256+o)*9+p)*64 + cg
    int cg = idx & 63;
    int p  = (idx >> 6) % 9;
    int bo = idx / 576;                         // b*256+o
    int o  = bo & 255;
    int b  = idx / 147456;
    const float* kp = kern + b * 1024 + cg * 16;
    float c0 = cogw[(o * 4 + 0) * 9 + p];
    float c1 = cogw[(o * 4 + 1) * 9 + p];
    float c2 = cogw[(o * 4 + 2) * 9 + p];
    float c3 = cogw[(o * 4 + 3) * 9 + p];
    u16x4 outv;
#pragma unroll
    for (int i = 0; i < 4; ++i) {
        f32x4 k4 = *(const f32x4*)(kp + i * 4);
        float cw = k4.x * c0 + k4.y * c1 + k4.z * c2 + k4.w * c3;
        float sg = 1.0f / (1.0f + __expf(-cw));
        float wv = wgt[(o * 256 + cg * 4 + i) * 9 + p];
        outv[i] = f2bf(sg * wv);
    }
    *(u16x4*)(dynw + ((size_t)bo * 9 + p) * 256 + cg * 4) = outv;
}

// ---------------- Stage 5: per-sample conv via implicit GEMM + MFMA --------
// Block tile: 256 o x 112 s (2 output rows). 4 waves; wave = 64 o x 112 s.
// K-loop: 8 chunks of 32 c; per chunk 9 taps as 9 shifted GEMM steps.
// LDS X tile transposed [4 rows][58 cols][c, pad 40] -> B-frag = ds_read_b128.
// x converted f32 -> bf16 during staging. grid 896 (= 32 b * 28 s-tiles).
#define LDSW 40
__global__ __launch_bounds__(256, 2) void conv_kernel(const float* __restrict__ x,
                                                      const u16* __restrict__ dynw,
                                                      float* __restrict__ out) {
    __shared__ u16 lds[4 * 58 * LDSW];          // 18,560 B
    const int tid = threadIdx.x;
    const int wave = tid >> 6, lane = tid & 63;
    const int l15 = lane & 15, quad = lane >> 4;
    const int gid = blockIdx.x;
    const int slot = gid >> 3;
    const int b = (gid & 7) * 4 + slot / 28;    // same-XCD blocks share b-slabs
    const int stile = slot % 28;
    const int y0 = stile * 2;

    // zero halo columns xx=0 and xx=57 once (value is 0 for every chunk)
    for (int i = tid; i < 320; i += 256) {
        int side = i & 1, j = i >> 1;
        int yy = j / LDSW, c = j % LDSW;
        lds[(yy * 58 + (side ? 57 : 0)) * LDSW + c] = 0;
    }

    f32x4 acc[4][7];
#pragma unroll
    for (int mf = 0; mf < 4; ++mf)
#pragma unroll
        for (int nf = 0; nf < 7; ++nf) acc[mf][nf] = (f32x4){0.f, 0.f, 0.f, 0.f};

    int bbase[7];
#pragma unroll
    for (int nf = 0; nf < 7; ++nf) {
        int n = nf * 16 + l15;                  // s within the 112-tile
        int r = (n >= 56) ? 1 : 0;
        int xx = n - 56 * r;
        bbase[nf] = (r * 58 + xx) * LDSW + quad * 8;
    }
    const u16* Abase = dynw + ((size_t)b * 256 + wave * 64 + l15) * 2304 + quad * 8;
    const float* Xb = x + (size_t)b * 256 * 3136;

    __syncthreads();
    for (int cc = 0; cc < 8; ++cc) {
        // stage 32 c x 4 rows x 56 cols, f32->bf16 transposed (c innermost)
#pragma unroll
        for (int it = 0; it < 7; ++it) {
            int i = it * 256 + tid;             // 1792 = 32c * 4yy * 14 xg
            int c = i / 56, rem = i % 56;
            int yy = rem / 14, xg = rem % 14;
            int yg = y0 - 1 + yy;
            f32x4 v = (f32x4){0.f, 0.f, 0.f, 0.f};
            if ((unsigned)yg < 56u)
                v = *(const f32x4*)(Xb + ((size_t)(cc * 32 + c) * 56 + yg) * 56 + xg * 4);
            int base = (yy * 58 + 1 + xg * 4) * LDSW + c;
            lds[base]            = f2bf(v.x);
            lds[base + LDSW]     = f2bf(v.y);
            lds[base + 2 * LDSW] = f2bf(v.z);
            lds[base + 3 * LDSW] = f2bf(v.w);
        }
        __syncthreads();
#pragma unroll
        for (int p = 0; p < 9; ++p) {
            const int dy = p / 3, dx = p % 3;
            const int tapoff = (dy * 58 + dx) * LDSW;
            s16x8 a0 = *(const s16x8*)(Abase + 0 * 36864 + p * 256 + cc * 32);
            s16x8 a1 = *(const s16x8*)(Abase + 1 * 36864 + p * 256 + cc * 32);
            s16x8 a2 = *(const s16x8*)(Abase + 2 * 36864 + p * 256 + cc * 32);
            s16x8 a3 = *(const s16x8*)(Abase + 3 * 36864 + p * 256 + cc * 32);
#pragma unroll
            for (int nf = 0; nf < 7; ++nf) {
                s16x8 bf = *(const s16x8*)(&lds[bbase[nf] + tapoff]);
                acc[0][nf] = __builtin_amdgcn_mfma_f32_16x16x32_bf16(a0, bf, acc[0][nf], 0, 0, 0);
                acc[1][nf] = __builtin_amdgcn_mfma_f32_16x16x32_bf16(a1, bf, acc[1][nf], 0, 0, 0);
                acc[2][nf] = __builtin_amdgcn_mfma_f32_16x16x32_bf16(a2, bf, acc[2][nf], 0, 0, 0);
                acc[3][nf] = __builtin_amdgcn_mfma_f32_16x16x32_bf16(a3, bf, acc[3][nf], 0, 0, 0);
            }
        }
        __syncthreads();
    }
    // epilogue: D[row=quad*4+r][col=l15] (m89/m91-verified C/D layout)
#pragma unroll
    for (int mf = 0; mf < 4; ++mf) {
        int o = wave * 64 + mf * 16 + quad * 4;
        size_t obase = ((size_t)b * 256 + o) * 3136 + (size_t)stile * 112 + l15;
#pragma unroll
        for (int nf = 0; nf < 7; ++nf) {
#pragma unroll
            for (int r = 0; r < 4; ++r)
                out[obase + (size_t)r * 3136 + nf * 16] = acc[mf][nf][r];
        }
    }
}

extern "C" void kernel_launch(void* const* d_in, const int* in_sizes, int n_in,
                              void* d_out, int out_size, void* d_ws, size_t ws_size,
                              hipStream_t stream) {
    const float* x    = (const float*)d_in[0];   // [32,256,56,56] f32
    const float* fc1w = (const float*)d_in[1];   // [256,256]
    const float* fc2w = (const float*)d_in[2];   // [1024,256]
    const float* fc2b = (const float*)d_in[3];   // [1024]
    const float* cogw = (const float*)d_in[4];   // [256,4,3,3]
    const float* wgt  = (const float*)d_in[5];   // [256,256,3,3]
    float* out = (float*)d_out;                  // [32,256,56,56] f32

    char* ws = (char*)d_ws;
    float* pooled = (float*)ws;              // 32 KB
    float* h      = (float*)(ws + 32768);    // 32 KB
    float* kern   = (float*)(ws + 65536);    // 128 KB
    u16*   dynw   = (u16*)(ws + 196608);     // 37.75 MB, [b][o][p][c] bf16

    pool_kernel<<<8192, 256, 0, stream>>>(x, pooled);
    fc1_kernel<<<2048, 256, 0, stream>>>(pooled, fc1w, h);
    fc2_kernel<<<8192, 256, 0, stream>>>(h, fc2w, fc2b, kern);
    dynw_kernel<<<18432, 256, 0, stream>>>(kern, cogw, wgt, dynw);
    conv_kernel<<<896, 256, 0, stream>>>(x, dynw, out);
}

// Round 3
// 384.601 us; speedup vs baseline: 1.0267x; 1.0267x over previous
//
#include <hip/hip_runtime.h>

typedef unsigned short u16;
typedef __attribute__((ext_vector_type(4))) float f32x4;
typedef __attribute__((ext_vector_type(8))) short s16x8;
typedef __attribute__((ext_vector_type(4))) unsigned short u16x4;

static __device__ __forceinline__ u16 f2bf(float f) {
    unsigned int x = __float_as_uint(f);
    x += 0x7fffu + ((x >> 16) & 1u);           // round-to-nearest-even
    return (u16)(x >> 16);
}

// ---------------- Stage 1: pooled[b][c] = mean_{h,w} x[b,c,h,w] -------------
// grid 8192 (= B*C), block 256
__global__ __launch_bounds__(256) void pool_kernel(const float* __restrict__ x,
                                                   float* __restrict__ pooled) {
    int bc = blockIdx.x;
    const float* p = x + (size_t)bc * 3136;
    float s = 0.f;
    for (int i = threadIdx.x; i < 784; i += 256) {       // 784*4 = 3136
        f32x4 v = *(const f32x4*)(p + i * 4);
        s += v.x + v.y + v.z + v.w;
    }
#pragma unroll
    for (int off = 32; off; off >>= 1) s += __shfl_xor(s, off);
    __shared__ float red[4];
    int lane = threadIdx.x & 63, wave = threadIdx.x >> 6;
    if (lane == 0) red[wave] = s;
    __syncthreads();
    if (threadIdx.x == 0)
        pooled[bc] = (red[0] + red[1] + red[2] + red[3]) * (1.0f / 3136.0f);
}

// ---------------- Stage 2: h[b][i] = relu(sum_j pooled[b][j]*fc1_w[i][j]) ---
__global__ __launch_bounds__(256) void fc1_kernel(const float* __restrict__ pooled,
                                                  const float* __restrict__ w,
                                                  float* __restrict__ h) {
    __shared__ float pv[256];
    int b = blockIdx.x >> 6;
    pv[threadIdx.x] = pooled[b * 256 + threadIdx.x];
    __syncthreads();
    int lane = threadIdx.x & 63, wave = threadIdx.x >> 6;
    int i = ((blockIdx.x & 63) << 2) + wave;
    f32x4 v = *(const f32x4*)(w + i * 256 + lane * 4);
    float s = v.x * pv[lane * 4 + 0] + v.y * pv[lane * 4 + 1] +
              v.z * pv[lane * 4 + 2] + v.w * pv[lane * 4 + 3];
#pragma unroll
    for (int off = 32; off; off >>= 1) s += __shfl_xor(s, off);
    if (lane == 0) h[b * 256 + i] = fmaxf(s, 0.f);
}

// ---------------- Stage 3: kern[b][oc] = sum_j h[b][j]*fc2_w[oc][j] + b -----
__global__ __launch_bounds__(256) void fc2_kernel(const float* __restrict__ h,
                                                  const float* __restrict__ w,
                                                  const float* __restrict__ bias,
                                                  float* __restrict__ kern) {
    __shared__ float hv[256];
    int b = blockIdx.x >> 8;
    hv[threadIdx.x] = h[b * 256 + threadIdx.x];
    __syncthreads();
    int lane = threadIdx.x & 63, wave = threadIdx.x >> 6;
    int i = ((blockIdx.x & 255) << 2) + wave;
    f32x4 v = *(const f32x4*)(w + i * 256 + lane * 4);
    float s = v.x * hv[lane * 4 + 0] + v.y * hv[lane * 4 + 1] +
              v.z * hv[lane * 4 + 2] + v.w * hv[lane * 4 + 3];
#pragma unroll
    for (int off = 32; off; off >>= 1) s += __shfl_xor(s, off);
    if (lane == 0) kern[b * 1024 + i] = s + bias[i];
}

// ---------------- Stage 4: dynw[b][o][p][c] = bf16(sigmoid(cw)*weight) -----
// cw[b,o,c,p] = sum_t kern[b, c*4+t] * cog[o, t, p]
// Block = (bg, o): wgt[o] slab staged coalesced into LDS; thread = c; loops
// 8 batches. All global reads/writes coalesced. grid 1024 (= 4 bg * 256 o).
__global__ __launch_bounds__(256) void dynw_kernel(const float* __restrict__ kern,
                                                   const float* __restrict__ cogw,
                                                   const float* __restrict__ wgt,
                                                   u16* __restrict__ dynw) {
    __shared__ float wl[2304];                  // wgt[o][256 c][9 p]
    const int o = blockIdx.x & 255;
    const int bg = blockIdx.x >> 8;             // 0..3 -> 8 batches each
    const int c = threadIdx.x;
    const float* wo = wgt + (size_t)o * 2304;
#pragma unroll
    for (int j = 0; j < 9; ++j)                 // fully coalesced
        wl[j * 256 + c] = wo[j * 256 + c];
    __syncthreads();

    float cg0[9], cg1[9], cg2[9], cg3[9];       // cog[o][t][p] — wave-uniform
#pragma unroll
    for (int p = 0; p < 9; ++p) {
        cg0[p] = cogw[(o * 4 + 0) * 9 + p];
        cg1[p] = cogw[(o * 4 + 1) * 9 + p];
        cg2[p] = cogw[(o * 4 + 2) * 9 + p];
        cg3[p] = cogw[(o * 4 + 3) * 9 + p];
    }
    float w9[9];                                // stride-9 LDS read: odd -> conflict-free
#pragma unroll
    for (int p = 0; p < 9; ++p) w9[p] = wl[c * 9 + p];

    for (int b = bg * 8; b < bg * 8 + 8; ++b) {
        f32x4 k4 = *(const f32x4*)(kern + b * 1024 + c * 4);
        u16* dst = dynw + (size_t)(b * 256 + o) * 9 * 256 + c;
#pragma unroll
        for (int p = 0; p < 9; ++p) {
            float cw = k4.x * cg0[p] + k4.y * cg1[p] + k4.z * cg2[p] + k4.w * cg3[p];
            float sg = 1.0f / (1.0f + __expf(-cw));
            dst[p * 256] = f2bf(sg * w9[p]);    // coalesced per (b,p)
        }
    }
}

// ---------------- Stage 5: per-sample conv via implicit GEMM + MFMA --------
// Block tile: 256 o x 112 s (2 output rows). 4 waves; wave = 64 o x 112 s.
// K-loop: 8 chunks of 32 c; per chunk 9 taps as 9 shifted GEMM steps.
// LDS X tile transposed [4 rows][58 cols][c, pad 40] -> B-frag = ds_read_b128.
// Staging: thread = (c-quad, yy, xx); 4 stride-plane f32 loads -> 1 ds_write_b64.
#define LDSW 40
__global__ __launch_bounds__(256, 2) void conv_kernel(const float* __restrict__ x,
                                                      const u16* __restrict__ dynw,
                                                      float* __restrict__ out) {
    __shared__ u16 lds[4 * 58 * LDSW];          // 18,560 B
    const int tid = threadIdx.x;
    const int wave = tid >> 6, lane = tid & 63;
    const int l15 = lane & 15, quad = lane >> 4;
    const int gid = blockIdx.x;
    const int slot = gid >> 3;
    const int b = (gid & 7) * 4 + slot / 28;    // same-XCD blocks share b-slabs
    const int stile = slot % 28;
    const int y0 = stile * 2;

    // zero halo columns xx=0 and xx=57 once (valid for every chunk), b64 writes
    if (tid < 64) {
        int side = tid & 1, yy = (tid >> 1) & 3, cg = tid >> 3;
        *(u16x4*)&lds[(yy * 58 + (side ? 57 : 0)) * LDSW + cg * 4] = (u16x4){0, 0, 0, 0};
    }

    f32x4 acc[4][7];
#pragma unroll
    for (int mf = 0; mf < 4; ++mf)
#pragma unroll
        for (int nf = 0; nf < 7; ++nf) acc[mf][nf] = (f32x4){0.f, 0.f, 0.f, 0.f};

    int bbase[7];
#pragma unroll
    for (int nf = 0; nf < 7; ++nf) {
        int n = nf * 16 + l15;                  // s within the 112-tile
        int r = (n >= 56) ? 1 : 0;
        int xx = n - 56 * r;
        bbase[nf] = (r * 58 + xx) * LDSW + quad * 8;
    }
    const u16* Abase = dynw + ((size_t)b * 256 + wave * 64 + l15) * 2304 + quad * 8;
    const float* Xb = x + (size_t)b * 256 * 3136;

    __syncthreads();
    for (int cc = 0; cc < 8; ++cc) {
        // stage 32 c x 4 rows x 56 cols: 4 plane-strided loads -> one b64 write
#pragma unroll
        for (int it = 0; it < 7; ++it) {
            int i = it * 256 + tid;             // 1792 = 8 cg * 4 yy * 56 xx
            int q = i / 56;
            int xx = i - q * 56;
            int yy = q & 3;
            int cg = q >> 2;
            int yg = y0 - 1 + yy;
            u16x4 w = (u16x4){0, 0, 0, 0};
            if ((unsigned)yg < 56u) {
                const float* src = Xb + (size_t)(cc * 32 + cg * 4) * 3136 + yg * 56 + xx;
                w.x = f2bf(src[0]);
                w.y = f2bf(src[3136]);
                w.z = f2bf(src[2 * 3136]);
                w.w = f2bf(src[3 * 3136]);
            }
            *(u16x4*)&lds[(yy * 58 + 1 + xx) * LDSW + cg * 4] = w;   // 8B-aligned
        }
        __syncthreads();
#pragma unroll
        for (int p = 0; p < 9; ++p) {
            const int dy = p / 3, dx = p % 3;
            const int tapoff = (dy * 58 + dx) * LDSW;
            s16x8 a0 = *(const s16x8*)(Abase + 0 * 36864 + p * 256 + cc * 32);
            s16x8 a1 = *(const s16x8*)(Abase + 1 * 36864 + p * 256 + cc * 32);
            s16x8 a2 = *(const s16x8*)(Abase + 2 * 36864 + p * 256 + cc * 32);
            s16x8 a3 = *(const s16x8*)(Abase + 3 * 36864 + p * 256 + cc * 32);
#pragma unroll
            for (int nf = 0; nf < 7; ++nf) {
                s16x8 bf = *(const s16x8*)(&lds[bbase[nf] + tapoff]);
                acc[0][nf] = __builtin_amdgcn_mfma_f32_16x16x32_bf16(a0, bf, acc[0][nf], 0, 0, 0);
                acc[1][nf] = __builtin_amdgcn_mfma_f32_16x16x32_bf16(a1, bf, acc[1][nf], 0, 0, 0);
                acc[2][nf] = __builtin_amdgcn_mfma_f32_16x16x32_bf16(a2, bf, acc[2][nf], 0, 0, 0);
                acc[3][nf] = __builtin_amdgcn_mfma_f32_16x16x32_bf16(a3, bf, acc[3][nf], 0, 0, 0);
            }
        }
        __syncthreads();
    }
    // epilogue: D[row=quad*4+r][col=l15] (m89/m91-verified C/D layout)
#pragma unroll
    for (int mf = 0; mf < 4; ++mf) {
        int o = wave * 64 + mf * 16 + quad * 4;
        size_t obase = ((size_t)b * 256 + o) * 3136 + (size_t)stile * 112 + l15;
#pragma unroll
        for (int nf = 0; nf < 7; ++nf) {
#pragma unroll
            for (int r = 0; r < 4; ++r)
                out[obase + (size_t)r * 3136 + nf * 16] = acc[mf][nf][r];
        }
    }
}

extern "C" void kernel_launch(void* const* d_in, const int* in_sizes, int n_in,
                              void* d_out, int out_size, void* d_ws, size_t ws_size,
                              hipStream_t stream) {
    const float* x    = (const float*)d_in[0];   // [32,256,56,56] f32
    const float* fc1w = (const float*)d_in[1];   // [256,256]
    const float* fc2w = (const float*)d_in[2];   // [1024,256]
    const float* fc2b = (const float*)d_in[3];   // [1024]
    const float* cogw = (const float*)d_in[4];   // [256,4,3,3]
    const float* wgt  = (const float*)d_in[5];   // [256,256,3,3]
    float* out = (float*)d_out;                  // [32,256,56,56] f32

    char* ws = (char*)d_ws;
    float* pooled = (float*)ws;              // 32 KB
    float* h      = (float*)(ws + 32768);    // 32 KB
    float* kern   = (float*)(ws + 65536);    // 128 KB
    u16*   dynw   = (u16*)(ws + 196608);     // 37.75 MB, [b][o][p][c] bf16

    pool_kernel<<<8192, 256, 0, stream>>>(x, pooled);
    fc1_kernel<<<2048, 256, 0, stream>>>(pooled, fc1w, h);
    fc2_kernel<<<8192, 256, 0, stream>>>(h, fc2w, fc2b, kern);
    dynw_kernel<<<1024, 256, 0, stream>>>(kern, cogw, wgt, dynw);
    conv_kernel<<<896, 256, 0, stream>>>(x, dynw, out);
}